// Round 1
// baseline (792.147 us; speedup 1.0000x reference)
//
#include <hip/hip_runtime.h>
#include <stdint.h>

// Problem constants
#define BB 32
#define HH 8
#define NQ 64
#define NK 4096
#define DIN 512
#define DV 64
#define DM 512

typedef unsigned short ushort_t;
typedef short bf16x8 __attribute__((ext_vector_type(8)));
typedef short bf16x4 __attribute__((ext_vector_type(4)));
typedef float f32x4 __attribute__((ext_vector_type(4)));

__device__ __forceinline__ unsigned short f2bf(float f) {
  union { float f; unsigned u; } v; v.f = f;
  unsigned r = v.u + 0x7fffu + ((v.u >> 16) & 1u);   // RNE
  return (unsigned short)(r >> 16);
}

// async global->LDS, 16B per lane. lds ptr must be wave-uniform; HW adds lane*16.
__device__ __forceinline__ void gld_lds16(const void* g, void* l) {
  __builtin_amdgcn_global_load_lds(
      (const __attribute__((address_space(1))) void*)g,
      (__attribute__((address_space(3))) void*)l, 16, 0, 0);
}

// ---------------------------------------------------------------------------
// K0: fp32 -> bf16 elementwise (for W_v, W_o). n must be multiple of 1024.
__global__ __launch_bounds__(256) void convf2bf(const float* __restrict__ in,
                                                unsigned short* __restrict__ out) {
  long i = (long)(blockIdx.x * 256 + threadIdx.x) * 4;
  f32x4 d = *(const f32x4*)(in + i);
  bf16x4 o;
  o[0] = (short)f2bf(d[0]); o[1] = (short)f2bf(d[1]);
  o[2] = (short)f2bf(d[2]); o[3] = (short)f2bf(d[3]);
  *(bf16x4*)(out + i) = o;
}

// ---------------------------------------------------------------------------
// K1: P[b][m=(h*64+q)][k] = exp(att12*att3)/Z, bf16, normalized. One block per (b,h,q).
// k = ch*256 + fh*64 + cw*4 + fw ; att12[b][ch][cw][h][fh][fw] ; att3[b][h][q][ch*16+cw]
__global__ __launch_bounds__(256) void ez_kernel(const float* __restrict__ att12,
                                                 const float* __restrict__ att3,
                                                 unsigned short* __restrict__ P) {
  const int bhq = blockIdx.x;          // = b*512 + h*64 + q
  const int h = (bhq >> 6) & 7;
  const int b = bhq >> 9;
  const int t = threadIdx.x;
  const int lane = t & 63, wave = t >> 6;

  const float* a3p = att3 + (long)bhq * 256;   // att3[b][h][q][*], same flat index order
  float vals[16];
  float sum = 0.f;
#pragma unroll
  for (int cch = 0; cch < 2; ++cch) {
    int kbase = cch * 2048 + t * 8;           // multiple of 8: fixed (ch, fh), 2 cw, 4 fw
    int ch = kbase >> 8;
    int fh = (kbase >> 6) & 3;
    int cw0 = (kbase >> 2) & 15;              // even
    const float* a12p = att12 + ((((long)(b * 16 + ch) * 16) * 8 + h) * 4 + fh) * 4;
    float y0 = a3p[ch * 16 + cw0];
    float y1 = a3p[ch * 16 + cw0 + 1];
#pragma unroll
    for (int j = 0; j < 8; ++j) {
      int cw = cw0 + (j >> 2);
      int fw = j & 3;
      float x = a12p[(long)cw * 128 + fw];
      float y = (j < 4) ? y0 : y1;
      float e = __expf(x * y);                // logits in [0,1]: no max-subtract needed
      vals[cch * 8 + j] = e;
      sum += e;
    }
  }
  // block reduction
  float s = sum;
#pragma unroll
  for (int off = 32; off > 0; off >>= 1) s += __shfl_down(s, off);
  __shared__ float red[4];
  if (lane == 0) red[wave] = s;
  __syncthreads();
  float Z = red[0] + red[1] + red[2] + red[3];
  float rZ = 1.0f / Z;
#pragma unroll
  for (int cch = 0; cch < 2; ++cch) {
    int kbase = cch * 2048 + t * 8;
    bf16x8 pk;
#pragma unroll
    for (int j = 0; j < 8; ++j) pk[j] = (short)f2bf(vals[cch * 8 + j] * rZ);
    *(bf16x8*)(P + (long)bhq * 4096 + kbase) = pk;
  }
}

// ---------------------------------------------------------------------------
// K2: values fp32 [b][k][c] -> Vt bf16 [b][c][k]  (64x64 tiles through LDS)
__global__ __launch_bounds__(256) void transpose_conv(const float* __restrict__ V,
                                                      unsigned short* __restrict__ Vt) {
  int id = blockIdx.x;
  int kt = id & 63;           // 64 k-tiles
  int ct = (id >> 6) & 7;     // 8 c-tiles
  int b = id >> 9;
  const int t = threadIdx.x;
  __shared__ __align__(16) unsigned short T[64][72];  // pad 72: rows 144B (16B mult)

  const float* vp = V + (long)b * (4096L * 512) + (long)(kt * 64) * 512 + ct * 64;
  int cc = (t & 15) * 4;
  int kk0 = t >> 4;
#pragma unroll
  for (int r = 0; r < 4; ++r) {
    int kk = kk0 + r * 16;
    f32x4 d = *(const f32x4*)(vp + (long)kk * 512 + cc);
    T[cc + 0][kk] = f2bf(d[0]);
    T[cc + 1][kk] = f2bf(d[1]);
    T[cc + 2][kk] = f2bf(d[2]);
    T[cc + 3][kk] = f2bf(d[3]);
  }
  __syncthreads();
  unsigned short* op = Vt + (long)b * (512L * 4096) + (long)(ct * 64) * 4096 + (long)(kt * 64);
#pragma unroll
  for (int s = 0; s < 2; ++s) {
    int li = s * 256 + t;
    int c = li >> 3, k8 = (li & 7) * 8;
    bf16x8 d = *(const bf16x8*)(&T[c][k8]);
    *(bf16x8*)(op + (long)c * 4096 + k8) = d;
  }
}

// ---------------------------------------------------------------------------
// Generic bf16 GEMM, m97 structure: D[m][n] = sum_k A[m][k] * Bt[n][k]
// A row-major m x K (lda), Bt row-major n x K (ldb). 256 thr = 4 waves (2x2),
// wave tile (BM/2)x(BN/2) of 16x16x32 MFMAs. BK=32. Batched via blockIdx.z.
template <int BM, int BN, bool OUT_BF16, bool ADD_BIAS>
__global__ __launch_bounds__(256, 2) void gemm_bt(
    const unsigned short* __restrict__ A, const unsigned short* __restrict__ Bt,
    void* __restrict__ C, const float* __restrict__ bias,
    int K, int lda, int ldb, int ldc,
    long sA, long sB, int zmodB,
    long sC1, long sC2, int zdivC,
    long sBias, int zmodBias) {
  constexpr int BK = 32;
  const int t = threadIdx.x;
  const int lane = t & 63;
  const int wave = t >> 6;
  const int z = blockIdx.z;
  const int m0 = blockIdx.y * BM;
  const int n0 = blockIdx.x * BN;

  A += (long)z * sA + (long)m0 * lda;
  Bt += (long)(z % zmodB) * sB + (long)n0 * ldb;

  __shared__ __align__(16) unsigned short As[BM * BK];
  __shared__ __align__(16) unsigned short Bs[BN * BK];

  constexpr int TM = BM / 32;
  constexpr int TN = BN / 32;
  const int wm = (wave >> 1) * (BM / 2);
  const int wn = (wave & 1) * (BN / 2);
  const int l16 = lane & 15;
  const int quad = lane >> 4;

  f32x4 acc[TM][TN];
#pragma unroll
  for (int i = 0; i < TM; ++i)
#pragma unroll
    for (int j = 0; j < TN; ++j) acc[i][j] = (f32x4){0.f, 0.f, 0.f, 0.f};

  constexpr int ASHOT = (BM * 4) / 256;  // 16B chunks per thread
  constexpr int BSHOT = (BN * 4) / 256;

  for (int k0 = 0; k0 < K; k0 += BK) {
#pragma unroll
    for (int s = 0; s < ASHOT; ++s) {
      int li = s * 256 + t;
      int row = li >> 2, kq = (li & 3) * 8;
      gld_lds16(A + (long)row * lda + k0 + kq, (char*)As + (s * 256 + wave * 64) * 16);
    }
#pragma unroll
    for (int s = 0; s < BSHOT; ++s) {
      int li = s * 256 + t;
      int row = li >> 2, kq = (li & 3) * 8;
      gld_lds16(Bt + (long)row * ldb + k0 + kq, (char*)Bs + (s * 256 + wave * 64) * 16);
    }
    __syncthreads();   // drains vmcnt before barrier (compiler-inserted)
    bf16x8 af[TM], bfr[TN];
#pragma unroll
    for (int i = 0; i < TM; ++i)
      af[i] = *(const bf16x8*)(As + (wm + i * 16 + l16) * BK + quad * 8);
#pragma unroll
    for (int j = 0; j < TN; ++j)
      bfr[j] = *(const bf16x8*)(Bs + (wn + j * 16 + l16) * BK + quad * 8);
#pragma unroll
    for (int i = 0; i < TM; ++i)
#pragma unroll
      for (int j = 0; j < TN; ++j)
        acc[i][j] = __builtin_amdgcn_mfma_f32_16x16x32_bf16(af[i], bfr[j], acc[i][j], 0, 0, 0);
    __syncthreads();
  }

  // epilogue: C/D layout col=lane&15, row=quad*4+reg
  long coff = (long)(z / zdivC) * sC1 + (long)(z % zdivC) * sC2;
  const float* bp = nullptr;
  if (ADD_BIAS) bp = bias + (long)(z % zmodBias) * sBias + n0;
#pragma unroll
  for (int i = 0; i < TM; ++i) {
#pragma unroll
    for (int j = 0; j < TN; ++j) {
      int col = wn + j * 16 + l16;
#pragma unroll
      for (int r = 0; r < 4; ++r) {
        int row = wm + i * 16 + quad * 4 + r;
        float v = acc[i][j][r];
        if (ADD_BIAS) v += bp[col];
        long idx = coff + (long)(m0 + row) * ldc + (n0 + col);
        if (OUT_BF16) ((unsigned short*)C)[idx] = f2bf(v);
        else ((float*)C)[idx] = v;
      }
    }
  }
}

// ---------------------------------------------------------------------------
extern "C" void kernel_launch(void* const* d_in, const int* in_sizes, int n_in,
                              void* d_out, int out_size, void* d_ws, size_t ws_size,
                              hipStream_t stream) {
  const float* att12 = (const float*)d_in[0];
  const float* att3  = (const float*)d_in[1];
  const float* values = (const float*)d_in[2];
  const float* W_v = (const float*)d_in[3];
  const float* b_v = (const float*)d_in[4];
  const float* W_o = (const float*)d_in[5];
  const float* b_o = (const float*)d_in[6];
  float* out = (float*)d_out;

  char* ws = (char*)d_ws;
  unsigned short* P   = (unsigned short*)(ws);                 // 128 MB: [32][512][4096]
  unsigned short* Vt  = (unsigned short*)(ws + 134217728L);    // 128 MB: [32][512][4096]
  unsigned short* U   = (unsigned short*)(ws + 268435456L);    // 16 MB: [32][8][64][512]
  unsigned short* Vo  = (unsigned short*)(ws + 285212672L);    // 2 MB: [32][64][8][64]
  unsigned short* Wvb = (unsigned short*)(ws + 287309824L);    // 0.5 MB
  unsigned short* Wob = (unsigned short*)(ws + 287834112L);    // 0.5 MB

  convf2bf<<<dim3(256), dim3(256), 0, stream>>>(W_v, Wvb);
  convf2bf<<<dim3(256), dim3(256), 0, stream>>>(W_o, Wob);
  ez_kernel<<<dim3(16384), dim3(256), 0, stream>>>(att12, att3, P);
  transpose_conv<<<dim3(16384), dim3(256), 0, stream>>>(values, Vt);

  // U[b] = P[b] (512x4096) x Vt[b]^T -> 512x512 bf16 (already softmax-normalized)
  gemm_bt<128, 128, true, false><<<dim3(4, 4, 32), dim3(256), 0, stream>>>(
      P, Vt, U, nullptr, 4096, 4096, 4096, 512,
      2097152L, 2097152L, 32,
      262144L, 0L, 1,
      0L, 1);

  // Vo[b][q][h][d] = U[b][h] (64x512) x W_v[h*64..][*]^T + b_v[h*64..]
  gemm_bt<64, 64, true, true><<<dim3(1, 1, 256), dim3(256), 0, stream>>>(
      U, Wvb, Vo, b_v, 512, 512, 512, 512,
      32768L, 32768L, 8,
      32768L, 64L, 8,
      64L, 8);

  // out[(b,q)][e] = Vo (2048x512) x W_o^T + b_o, fp32
  gemm_bt<128, 128, false, true><<<dim3(4, 16, 1), dim3(256), 0, stream>>>(
      Vo, Wob, out, b_o, 512, 512, 512, 512,
      0L, 0L, 1,
      0L, 0L, 1,
      0L, 1);

  (void)in_sizes; (void)n_in; (void)out_size; (void)ws_size;
}

// Round 2
// 608.747 us; speedup vs baseline: 1.3013x; 1.3013x over previous
//
#include <hip/hip_runtime.h>
#include <stdint.h>

// Problem constants
#define BB 32
#define HH 8
#define NQ 64
#define NK 4096
#define DIN 512
#define DV 64
#define DM 512

typedef short bf16x8 __attribute__((ext_vector_type(8)));
typedef short bf16x4 __attribute__((ext_vector_type(4)));
typedef float f32x4 __attribute__((ext_vector_type(4)));

__device__ __forceinline__ unsigned short f2bf(float f) {
  union { float f; unsigned u; } v; v.f = f;
  unsigned r = v.u + 0x7fffu + ((v.u >> 16) & 1u);   // RNE
  return (unsigned short)(r >> 16);
}

// async global->LDS, 16B per lane. lds ptr must be wave-uniform; HW adds lane*16.
__device__ __forceinline__ void gld_lds16(const void* g, void* l) {
  __builtin_amdgcn_global_load_lds(
      (const __attribute__((address_space(1))) void*)g,
      (__attribute__((address_space(3))) void*)l, 16, 0, 0);
}

// ---------------------------------------------------------------------------
// K0: fp32 -> bf16 elementwise (for W_v, W_o). n = 262144 -> grid 256.
__global__ __launch_bounds__(256) void convf2bf(const float* __restrict__ in,
                                                unsigned short* __restrict__ out) {
  long i = (long)(blockIdx.x * 256 + threadIdx.x) * 4;
  f32x4 d = *(const f32x4*)(in + i);
  bf16x4 o;
  o[0] = (short)f2bf(d[0]); o[1] = (short)f2bf(d[1]);
  o[2] = (short)f2bf(d[2]); o[3] = (short)f2bf(d[3]);
  *(bf16x4*)(out + i) = o;
}

// ---------------------------------------------------------------------------
// K1: rZ[b,h,q] = 1 / sum_k exp(att12*att3). One wave per (b,h,q).
// k = ch*256 + fh*64 + cw*4 + fw ; att12 flat: (b*16+ch)*2048 + cw*128 + h*16 + fh*4 + fw
__global__ __launch_bounds__(64) void zsum_kernel(const float* __restrict__ att12,
                                                  const float* __restrict__ att3,
                                                  float* __restrict__ rZ) {
  const int bhq = blockIdx.x;          // = (b*8+h)*64+q
  const int h = (bhq >> 6) & 7;
  const int b = bhq >> 9;
  const int l = threadIdx.x;           // one wave
  const int ch = l >> 2, fh = l & 3;   // lane covers k = l*64 .. l*64+63 (all cw,fw)
  const float* a3p = att3 + (long)bhq * 256 + ch * 16;
  const float* a12p = att12 + (long)(b * 16 + ch) * 2048 + h * 16 + fh * 4;
  float sum = 0.f;
#pragma unroll
  for (int cw = 0; cw < 16; ++cw) {
    float y = a3p[cw];
    f32x4 x = *(const f32x4*)(a12p + cw * 128);
#pragma unroll
    for (int fw = 0; fw < 4; ++fw) sum += __expf(x[fw] * y);
  }
#pragma unroll
  for (int off = 32; off > 0; off >>= 1) sum += __shfl_down(sum, off);
  if (l == 0) rZ[bhq] = 1.0f / sum;
}

// ---------------------------------------------------------------------------
// K2: values fp32 [b][k][c] -> Vt bf16 [b][c][k]  (64x64 tiles through LDS)
__global__ __launch_bounds__(256) void transpose_conv(const float* __restrict__ V,
                                                      unsigned short* __restrict__ Vt) {
  int id = blockIdx.x;
  int kt = id & 63;           // 64 k-tiles
  int ct = (id >> 6) & 7;     // 8 c-tiles
  int b = id >> 9;
  const int t = threadIdx.x;
  __shared__ __align__(16) unsigned short T[64][72];  // pad 72

  const float* vp = V + (long)b * (4096L * 512) + (long)(kt * 64) * 512 + ct * 64;
  int cc = (t & 15) * 4;
  int kk0 = t >> 4;
#pragma unroll
  for (int r = 0; r < 4; ++r) {
    int kk = kk0 + r * 16;
    f32x4 d = *(const f32x4*)(vp + (long)kk * 512 + cc);
    T[cc + 0][kk] = f2bf(d[0]);
    T[cc + 1][kk] = f2bf(d[1]);
    T[cc + 2][kk] = f2bf(d[2]);
    T[cc + 3][kk] = f2bf(d[3]);
  }
  __syncthreads();
  unsigned short* op = Vt + (long)b * (512L * 4096) + (long)(ct * 64) * 4096 + (long)(kt * 64);
#pragma unroll
  for (int s = 0; s < 2; ++s) {
    int li = s * 256 + t;
    int c = li >> 3, k8 = (li & 7) * 8;
    bf16x8 d = *(const bf16x8*)(&T[c][k8]);
    *(bf16x8*)(op + (long)c * 4096 + k8) = d;
  }
}

// ---------------------------------------------------------------------------
// K3: fused U-GEMM. U[b][m=(h*64+q)][c] = rZ[b,m] * sum_k exp(a12*a3) * Vt[b][c][k]
// A-tile (128x32 bf16) generated in-register -> LDS. B staged via global_load_lds.
// Grid 512 flat; swizzle puts all 4 m-tiles of (b, n-strip) on one XCD.
__global__ __launch_bounds__(256, 2) void fused_u_gemm(
    const float* __restrict__ att12, const float* __restrict__ att3,
    const float* __restrict__ rZ, const unsigned short* __restrict__ Vt,
    unsigned short* __restrict__ U) {
  const int id = blockIdx.x;
  const int xcd = id & 7, rest = id >> 3;
  const int m_t = rest & 3, bh = rest >> 2;
  const int b = bh * 2 + (xcd & 1);
  const int n_t = xcd >> 1;
  const int m0 = m_t * 128, n0 = n_t * 128;
  const int t = threadIdx.x, lane = t & 63, wave = t >> 6;

  const unsigned short* Vb = Vt + (long)b * (512L * 4096) + (long)n0 * 4096;
  __shared__ __align__(16) unsigned short As[128 * 32];
  __shared__ __align__(16) unsigned short Bs[128 * 32];

  // A-gen assignment: thread t makes 16 k-values of row r
  const int r = t >> 1;
  const int kh = (t & 1) * 16;
  const int m = m0 + r, h = m >> 6, q = m & 63;
  const float* a3row = att3 + ((long)(b * 8 + h) * 64 + q) * 256;
  const float* a12bh = att12 + (long)b * 32768 + h * 16;  // + ch*2048 + cw*128 + fh*4 + fw

  const int wm = (wave >> 1) * 64, wn = (wave & 1) * 64;
  const int l16 = lane & 15, quad = lane >> 4;

  f32x4 acc[4][4];
#pragma unroll
  for (int i = 0; i < 4; ++i)
#pragma unroll
    for (int j = 0; j < 4; ++j) acc[i][j] = (f32x4){0.f, 0.f, 0.f, 0.f};

  for (int k0 = 0; k0 < 4096; k0 += 32) {
    // B staging: 2 shots x 256 lanes x 16B = 8 KB
    {
      int row = t >> 2, kq = (t & 3) * 8;
      gld_lds16(Vb + (long)row * 4096 + k0 + kq, (char*)Bs + (wave * 64) * 16);
      int li = 256 + t;
      row = li >> 2; kq = (li & 3) * 8;
      gld_lds16(Vb + (long)row * 4096 + k0 + kq, (char*)Bs + (256 + wave * 64) * 16);
    }
    // A generation: exp(att12*att3) -> bf16 -> LDS (row-major 128x32)
    {
      int k = k0 + kh;
      int ch = k >> 8, fh = (k >> 6) & 3, cw0 = (k >> 2) & 15;  // cw0 multiple of 4
      f32x4 y = *(const f32x4*)(a3row + ch * 16 + cw0);
      const float* a12p = a12bh + (long)ch * 2048 + cw0 * 128 + fh * 4;
      bf16x8 p0, p1;
#pragma unroll
      for (int c4 = 0; c4 < 2; ++c4) {
        f32x4 x = *(const f32x4*)(a12p + c4 * 128);
#pragma unroll
        for (int fw = 0; fw < 4; ++fw) p0[c4 * 4 + fw] = (short)f2bf(__expf(x[fw] * y[c4]));
      }
#pragma unroll
      for (int c4 = 2; c4 < 4; ++c4) {
        f32x4 x = *(const f32x4*)(a12p + c4 * 128);
#pragma unroll
        for (int fw = 0; fw < 4; ++fw) p1[(c4 - 2) * 4 + fw] = (short)f2bf(__expf(x[fw] * y[c4]));
      }
      *(bf16x8*)(As + r * 32 + kh) = p0;
      *(bf16x8*)(As + r * 32 + kh + 8) = p1;
    }
    __syncthreads();
    bf16x8 af[4], bfr[4];
#pragma unroll
    for (int i = 0; i < 4; ++i)
      af[i] = *(const bf16x8*)(As + (wm + i * 16 + l16) * 32 + quad * 8);
#pragma unroll
    for (int j = 0; j < 4; ++j)
      bfr[j] = *(const bf16x8*)(Bs + (wn + j * 16 + l16) * 32 + quad * 8);
#pragma unroll
    for (int i = 0; i < 4; ++i)
#pragma unroll
      for (int j = 0; j < 4; ++j)
        acc[i][j] = __builtin_amdgcn_mfma_f32_16x16x32_bf16(af[i], bfr[j], acc[i][j], 0, 0, 0);
    __syncthreads();
  }

  // epilogue: scale by rZ[row], store bf16 U[b][m][c]
  const float* rzb = rZ + (long)b * 512;
  unsigned short* Ub = U + (long)b * 262144;
#pragma unroll
  for (int i = 0; i < 4; ++i) {
#pragma unroll
    for (int j = 0; j < 4; ++j) {
      int col = n0 + wn + j * 16 + l16;
#pragma unroll
      for (int rr = 0; rr < 4; ++rr) {
        int row = m0 + wm + i * 16 + quad * 4 + rr;
        float v = acc[i][j][rr] * rzb[row];
        Ub[(long)row * 512 + col] = f2bf(v);
      }
    }
  }
}

// ---------------------------------------------------------------------------
// Generic bf16 GEMM (m97 structure) for the two small projections.
template <int BM, int BN, bool OUT_BF16, bool ADD_BIAS>
__global__ __launch_bounds__(256, 2) void gemm_bt(
    const unsigned short* __restrict__ A, const unsigned short* __restrict__ Bt,
    void* __restrict__ C, const float* __restrict__ bias,
    int K, int lda, int ldb, int ldc,
    long sA, long sB, int zmodB,
    long sC1, long sC2, int zdivC,
    long sBias, int zmodBias) {
  constexpr int BK = 32;
  const int t = threadIdx.x;
  const int lane = t & 63;
  const int wave = t >> 6;
  const int z = blockIdx.z;
  const int m0 = blockIdx.y * BM;
  const int n0 = blockIdx.x * BN;

  A += (long)z * sA + (long)m0 * lda;
  Bt += (long)(z % zmodB) * sB + (long)n0 * ldb;

  __shared__ __align__(16) unsigned short As[BM * BK];
  __shared__ __align__(16) unsigned short Bs[BN * BK];

  constexpr int TM = BM / 32;
  constexpr int TN = BN / 32;
  const int wm = (wave >> 1) * (BM / 2);
  const int wn = (wave & 1) * (BN / 2);
  const int l16 = lane & 15;
  const int quad = lane >> 4;

  f32x4 acc[TM][TN];
#pragma unroll
  for (int i = 0; i < TM; ++i)
#pragma unroll
    for (int j = 0; j < TN; ++j) acc[i][j] = (f32x4){0.f, 0.f, 0.f, 0.f};

  constexpr int ASHOT = (BM * 4) / 256;
  constexpr int BSHOT = (BN * 4) / 256;

  for (int k0 = 0; k0 < K; k0 += BK) {
#pragma unroll
    for (int s = 0; s < ASHOT; ++s) {
      int li = s * 256 + t;
      int row = li >> 2, kq = (li & 3) * 8;
      gld_lds16(A + (long)row * lda + k0 + kq, (char*)As + (s * 256 + wave * 64) * 16);
    }
#pragma unroll
    for (int s = 0; s < BSHOT; ++s) {
      int li = s * 256 + t;
      int row = li >> 2, kq = (li & 3) * 8;
      gld_lds16(Bt + (long)row * ldb + k0 + kq, (char*)Bs + (s * 256 + wave * 64) * 16);
    }
    __syncthreads();
    bf16x8 af[TM], bfr[TN];
#pragma unroll
    for (int i = 0; i < TM; ++i)
      af[i] = *(const bf16x8*)(As + (wm + i * 16 + l16) * BK + quad * 8);
#pragma unroll
    for (int j = 0; j < TN; ++j)
      bfr[j] = *(const bf16x8*)(Bs + (wn + j * 16 + l16) * BK + quad * 8);
#pragma unroll
    for (int i = 0; i < TM; ++i)
#pragma unroll
      for (int j = 0; j < TN; ++j)
        acc[i][j] = __builtin_amdgcn_mfma_f32_16x16x32_bf16(af[i], bfr[j], acc[i][j], 0, 0, 0);
    __syncthreads();
  }

  long coff = (long)(z / zdivC) * sC1 + (long)(z % zdivC) * sC2;
  const float* bp = nullptr;
  if (ADD_BIAS) bp = bias + (long)(z % zmodBias) * sBias + n0;
#pragma unroll
  for (int i = 0; i < TM; ++i) {
#pragma unroll
    for (int j = 0; j < TN; ++j) {
      int col = wn + j * 16 + l16;
#pragma unroll
      for (int r = 0; r < 4; ++r) {
        int row = wm + i * 16 + quad * 4 + r;
        float v = acc[i][j][r];
        if (ADD_BIAS) v += bp[col];
        long idx = coff + (long)(m0 + row) * ldc + (n0 + col);
        if (OUT_BF16) ((unsigned short*)C)[idx] = f2bf(v);
        else ((float*)C)[idx] = v;
      }
    }
  }
}

// ---------------------------------------------------------------------------
extern "C" void kernel_launch(void* const* d_in, const int* in_sizes, int n_in,
                              void* d_out, int out_size, void* d_ws, size_t ws_size,
                              hipStream_t stream) {
  const float* att12 = (const float*)d_in[0];
  const float* att3  = (const float*)d_in[1];
  const float* values = (const float*)d_in[2];
  const float* W_v = (const float*)d_in[3];
  const float* b_v = (const float*)d_in[4];
  const float* W_o = (const float*)d_in[5];
  const float* b_o = (const float*)d_in[6];
  float* out = (float*)d_out;

  char* ws = (char*)d_ws;
  unsigned short* Vt  = (unsigned short*)(ws);                 // 128 MB: [32][512][4096]
  unsigned short* U   = (unsigned short*)(ws + 134217728L);    // 16 MB: [32][512][512]
  unsigned short* Vo  = (unsigned short*)(ws + 150994944L);    // 2 MB: [32][64][8][64]
  unsigned short* Wvb = (unsigned short*)(ws + 153092096L);    // 0.5 MB
  unsigned short* Wob = (unsigned short*)(ws + 153616384L);    // 0.5 MB
  float*          rZ  = (float*)(ws + 154140672L);             // 64 KB: [32][512]

  convf2bf<<<dim3(256), dim3(256), 0, stream>>>(W_v, Wvb);
  convf2bf<<<dim3(256), dim3(256), 0, stream>>>(W_o, Wob);
  zsum_kernel<<<dim3(16384), dim3(64), 0, stream>>>(att12, att3, rZ);
  transpose_conv<<<dim3(16384), dim3(256), 0, stream>>>(values, Vt);

  // U[b] = softmax-attention applied to values (512x512 bf16 per batch)
  fused_u_gemm<<<dim3(512), dim3(256), 0, stream>>>(att12, att3, rZ, Vt, U);

  // Vo[b][q][h][d] = U[b][h] (64x512) x W_v[h*64..][*]^T + b_v[h*64..]
  gemm_bt<64, 64, true, true><<<dim3(1, 1, 256), dim3(256), 0, stream>>>(
      U, Wvb, Vo, b_v, 512, 512, 512, 512,
      32768L, 32768L, 8,
      32768L, 64L, 8,
      64L, 8);

  // out[(b,q)][e] = Vo (2048x512) x W_o^T + b_o, fp32
  gemm_bt<128, 128, false, true><<<dim3(4, 16, 1), dim3(256), 0, stream>>>(
      Vo, Wob, out, b_o, 512, 512, 512, 512,
      0L, 0L, 1,
      0L, 0L, 1,
      0L, 1);

  (void)in_sizes; (void)n_in; (void)out_size; (void)ws_size;
}